// Round 5
// baseline (143.401 us; speedup 1.0000x reference)
//
#include <hip/hip_runtime.h>
#include <math.h>

#define NROWS 32768
#define DDIM  1024
#define NEXP  64
#define BM    64
#define BK    128               // fp32 k per chunk -> K' = 256 bf16-concat
#define NCH   (DDIM / BK)       // 8 chunks
#define LSTR  264               // bf16 row stride (256 + 8 pad)
#define TAU   1e-3f             // repair margin (~250 sigma of logit error)
#define EPSF  1e-9f
#define CAPMAX 4096

typedef __attribute__((ext_vector_type(8)))  short  short8;
typedef __attribute__((ext_vector_type(16))) float  f32x16;

// stable greater-than: value desc, index asc on ties (matches lax.top_k)
__device__ __forceinline__ bool gt_(float a, int ea, float b, int eb)
{ return a > b || (a == b && ea < eb); }

// split f into bf16 hi (RN) + bf16 lo (RN of residual)
__device__ __forceinline__ void cvt_hl(float f, unsigned& h, unsigned& l)
{
    unsigned u  = __float_as_uint(f);
    unsigned hu = (u + 0x7FFFu + ((u >> 16) & 1u)) & 0xFFFF0000u;
    h = hu >> 16;
    float r = f - __uint_as_float(hu);
    unsigned v = __float_as_uint(r);
    l = (v + 0x7FFFu + ((v >> 16) & 1u)) >> 16;
}

__device__ __forceinline__ void cvt4(float4 f, uint2& hw, uint2& lw)
{
    unsigned h0,h1,h2,h3,l0,l1,l2,l3;
    cvt_hl(f.x,h0,l0); cvt_hl(f.y,h1,l1); cvt_hl(f.z,h2,l2); cvt_hl(f.w,h3,l3);
    hw.x = h0 | (h1 << 16); hw.y = h2 | (h3 << 16);
    lw.x = l0 | (l1 << 16); lw.y = l2 | (l3 << 16);
}

// ---------------------------------------------------------------------------
// Main: grid 512 x 256 thr. Block = 64 rows x 64 experts, K-chunks of 128.
// LDS per chunk: xs[64][256+pad] bf16 = [xh | xl], ws[64][256+pad] = [wh | wl].
// Waves: wm = wave&1 row-half (32 rows), ks = wave>>1 K'-half (128 of 256).
// Pass1 B = [wh|wl] (hh+ll terms); Pass2 B = k'+128 mod 256 (hl+lh terms).
// A-frags register-held across both passes. 2-way split-K' reduced via LDS.
// ---------------------------------------------------------------------------
__global__ __launch_bounds__(256, 2) void moe_mfma(
    const float* __restrict__ x, const float* __restrict__ gw,
    float* __restrict__ out, float* __restrict__ meanacc,
    int* __restrict__ cnt, int* __restrict__ list, int cap)
{
    extern __shared__ unsigned short lds[];          // 2 x [64][264] bf16
    unsigned short* xs  = lds;
    unsigned short* wsl = lds + 64 * LSTR;

    const int t    = threadIdx.x;
    const int wave = t >> 6, lane = t & 63;
    const int wm   = wave & 1;          // row half
    const int ks   = wave >> 1;         // k'-half
    const int l31  = lane & 31, l5 = lane >> 5;
    const int row0 = blockIdx.x * BM;

    f32x16 acc0, acc1;
    #pragma unroll
    for (int r = 0; r < 16; ++r) { acc0[r] = 0.0f; acc1[r] = 0.0f; }

    for (int c = 0; c < NCH; ++c) {
        __syncthreads();
        const int k0 = c * BK;
        // ---- stage + convert: 2048 float4 slots over [64 rows][32 f4] -----
        #pragma unroll
        for (int s = 0; s < 8; ++s) {
            int idx = t + 256 * s;
            int r = idx >> 5, cf4 = idx & 31;
            float4 xv = *reinterpret_cast<const float4*>(
                x + (size_t)(row0 + r) * DDIM + k0 + cf4 * 4);
            float4 wv = *reinterpret_cast<const float4*>(
                gw + (size_t)r * DDIM + k0 + cf4 * 4);
            uint2 hw, lw;
            cvt4(xv, hw, lw);
            *reinterpret_cast<uint2*>(xs + r * LSTR + cf4 * 4)       = hw;
            *reinterpret_cast<uint2*>(xs + r * LSTR + 128 + cf4 * 4) = lw;
            cvt4(wv, hw, lw);
            *reinterpret_cast<uint2*>(wsl + r * LSTR + cf4 * 4)       = hw;
            *reinterpret_cast<uint2*>(wsl + r * LSTR + 128 + cf4 * 4) = lw;
        }
        __syncthreads();
        // ---- A-fragments (held across both passes) ------------------------
        short8 a[8];
        #pragma unroll
        for (int i = 0; i < 8; ++i) {
            int kb = ks * 8 + i;
            a[i] = *reinterpret_cast<const short8*>(
                xs + (32 * wm + l31) * LSTR + kb * 16 + l5 * 8);
        }
        // ---- pass 1: B = [wh|wl]  (xh*wh + xl*wl) -------------------------
        #pragma unroll
        for (int i = 0; i < 8; ++i) {
            int kb = ks * 8 + i;
            short8 b0 = *reinterpret_cast<const short8*>(
                wsl + l31 * LSTR + kb * 16 + l5 * 8);
            short8 b1 = *reinterpret_cast<const short8*>(
                wsl + (32 + l31) * LSTR + kb * 16 + l5 * 8);
            acc0 = __builtin_amdgcn_mfma_f32_32x32x16_bf16(a[i], b0, acc0, 0, 0, 0);
            acc1 = __builtin_amdgcn_mfma_f32_32x32x16_bf16(a[i], b1, acc1, 0, 0, 0);
        }
        // ---- pass 2: B shifted k'+128 mod 256  (xh*wl + xl*wh) ------------
        #pragma unroll
        for (int i = 0; i < 8; ++i) {
            int kb = (ks * 8 + i + 8) & 15;
            short8 b0 = *reinterpret_cast<const short8*>(
                wsl + l31 * LSTR + kb * 16 + l5 * 8);
            short8 b1 = *reinterpret_cast<const short8*>(
                wsl + (32 + l31) * LSTR + kb * 16 + l5 * 8);
            acc0 = __builtin_amdgcn_mfma_f32_32x32x16_bf16(a[i], b0, acc0, 0, 0, 0);
            acc1 = __builtin_amdgcn_mfma_f32_32x32x16_bf16(a[i], b1, acc1, 0, 0, 0);
        }
    }

    // ---- 2-way split-K' reduction through LDS -----------------------------
    float* red = reinterpret_cast<float*>(lds);            // 4096 f32 = 16 KB
    __syncthreads();
    if (ks == 1) {
        #pragma unroll
        for (int r = 0; r < 16; ++r) {
            red[((wm * 2 + 0) * 16 + r) * 64 + lane] = acc0[r];
            red[((wm * 2 + 1) * 16 + r) * 64 + lane] = acc1[r];
        }
    }
    __syncthreads();
    float* lgs = reinterpret_cast<float*>(lds + 64 * LSTR);  // [64][68] f32
    if (ks == 0) {
        #pragma unroll
        for (int r = 0; r < 16; ++r) {
            acc0[r] += red[((wm * 2 + 0) * 16 + r) * 64 + lane];
            acc1[r] += red[((wm * 2 + 1) * 16 + r) * 64 + lane];
        }
        // C layout (m74/m101): col = lane&31, row = (reg&3) + 8*(reg>>2) + 4*(lane>>5)
        #pragma unroll
        for (int r = 0; r < 16; ++r) {
            int lrow = wm * 32 + (r & 3) + 8 * (r >> 2) + 4 * l5;
            lgs[lrow * 68 + l31]      = acc0[r];
            lgs[lrow * 68 + 32 + l31] = acc1[r];
        }
    }
    __syncthreads();

    // ---- row epilogue: 4 threads per row, 16 experts each -----------------
    const int erow = t >> 2, q = t & 3;   // lane = (erow%16)*4 + q
    float L[16];
    #pragma unroll
    for (int i = 0; i < 4; ++i) {
        float4 v = *reinterpret_cast<const float4*>(lgs + erow * 68 + q * 16 + i * 4);
        L[4*i] = v.x; L[4*i+1] = v.y; L[4*i+2] = v.z; L[4*i+3] = v.w;
    }
    float v1 = -3.4e38f, v2 = -3.4e38f, v3 = -3.4e38f;
    int   e1 = 1 << 30,  e2 = 1 << 30,  e3 = 1 << 30;
    #pragma unroll
    for (int i = 0; i < 16; ++i) {
        float v = L[i]; int e = q * 16 + i;
        if      (gt_(v, e, v1, e1)) { v3=v2; e3=e2; v2=v1; e2=e1; v1=v; e1=e; }
        else if (gt_(v, e, v2, e2)) { v3=v2; e3=e2; v2=v; e2=e; }
        else if (gt_(v, e, v3, e3)) { v3=v; e3=e; }
    }
    #pragma unroll
    for (int m = 1; m <= 2; m <<= 1) {   // merge the row's 4 lanes (xor on q bits)
        float o1 = __shfl_xor(v1, m), o2 = __shfl_xor(v2, m), o3 = __shfl_xor(v3, m);
        int  oe1 = __shfl_xor(e1, m), oe2 = __shfl_xor(e2, m), oe3 = __shfl_xor(e3, m);
        float n1, n2, n3; int m1, m2, m3;
        if (gt_(v1, e1, o1, oe1)) {
            n1 = v1; m1 = e1;
            if (gt_(v2, e2, o1, oe1)) {
                n2 = v2; m2 = e2;
                if (gt_(v3, e3, o1, oe1)) { n3 = v3; m3 = e3; } else { n3 = o1; m3 = oe1; }
            } else {
                n2 = o1; m2 = oe1;
                if (gt_(v2, e2, o2, oe2)) { n3 = v2; m3 = e2; } else { n3 = o2; m3 = oe2; }
            }
        } else {
            n1 = o1; m1 = oe1;
            if (gt_(o2, oe2, v1, e1)) {
                n2 = o2; m2 = oe2;
                if (gt_(o3, oe3, v1, e1)) { n3 = o3; m3 = oe3; } else { n3 = v1; m3 = e1; }
            } else {
                n2 = v1; m2 = e1;
                if (gt_(o2, oe2, v2, e2)) { n3 = o2; m3 = oe2; } else { n3 = v2; m3 = e2; }
            }
        }
        v1 = n1; e1 = m1; v2 = n2; e2 = m2; v3 = n3; e3 = m3;
    }
    float pr[16], sl = 0.0f;
    #pragma unroll
    for (int i = 0; i < 16; ++i) { pr[i] = expf(L[i] - v1); sl += pr[i]; }
    float S = sl;
    S += __shfl_xor(S, 1); S += __shfl_xor(S, 2);
    const float invS = 1.0f / S;
    #pragma unroll
    for (int i = 0; i < 16; ++i) pr[i] *= invS;
    // per-expert partial sums across this wave's 16 rows (xor on row bits)
    #pragma unroll
    for (int m = 4; m <= 32; m <<= 1)
        #pragma unroll
        for (int i = 0; i < 16; ++i) pr[i] += __shfl_xor(pr[i], m);
    float* auxred = lgs + 64 * 68;       // 4 waves x 64 experts
    if (lane < 4) {
        #pragma unroll
        for (int i = 0; i < 16; ++i) auxred[wave * 64 + q * 16 + i] = pr[i];
    }
    if (q == 0) {
        const float p1 = invS;                    // exp(v1-v1)*invS
        const float p2 = expf(v2 - v1) * invS;
        const float dn = p1 + p2 + EPSF;
        const int r = row0 + erow;
        out[2 * r]                 = p1 / dn;
        out[2 * r + 1]             = p2 / dn;
        out[2 * NROWS + 2 * r]     = (float)e1;
        out[2 * NROWS + 2 * r + 1] = (float)e2;
        if (cap > 0 && (v1 - v2 < TAU || v2 - v3 < TAU)) {
            int pos = atomicAdd(cnt, 1);
            if (pos < cap) list[pos] = r;
        }
    }
    __syncthreads();
    if (t < 64) {
        float s = auxred[t] + auxred[64 + t] + auxred[128 + t] + auxred[192 + t];
        atomicAdd(&meanacc[t], s);
    }
}

__global__ void prep_kernel(float* __restrict__ meanacc, int* __restrict__ cnt, int cap)
{
    int t = threadIdx.x;
    if (t < 64) meanacc[t] = 0.0f;
    if (t == 64 && cap > 0) *cnt = 0;
}

// ---------------------------------------------------------------------------
// Finalize: block 0 computes aux loss; blocks 1..64 repair flagged rows with
// exact fp32 logits (overwrites weights+indices for those rows).
// ---------------------------------------------------------------------------
__global__ __launch_bounds__(256) void finalize_kernel(
    const float* __restrict__ x, const float* __restrict__ gw,
    float* __restrict__ out, const float* __restrict__ meanacc,
    const int* __restrict__ cnt, const int* __restrict__ list, int cap)
{
    if (blockIdx.x == 0) {
        int e = threadIdx.x;
        if (e < 64) {
            float m = meanacc[e] * (1.0f / (float)NROWS);
            float v = m * logf(m + EPSF);
            #pragma unroll
            for (int k = 1; k <= 32; k <<= 1) v += __shfl_xor(v, k);
            if (e == 0) out[4 * NROWS] = v;
        }
        return;
    }
    __shared__ float lg[64];
    const int n = (cap > 0) ? min(*cnt, cap) : 0;
    const int tt = threadIdx.x, e = tt >> 2, part = tt & 3;
    for (int j = (int)blockIdx.x - 1; j < n; j += 64) {
        const int row = list[j];
        const float* xr = x  + (size_t)row * DDIM + part * 256;
        const float* wr = gw + (size_t)e   * DDIM + part * 256;
        float a = 0.0f;
        #pragma unroll 8
        for (int kk = 0; kk < 64; ++kk) {
            float4 xv = *reinterpret_cast<const float4*>(xr + kk * 4);
            float4 wv = *reinterpret_cast<const float4*>(wr + kk * 4);
            a += xv.x * wv.x + xv.y * wv.y + xv.z * wv.z + xv.w * wv.w;
        }
        a += __shfl_xor(a, 1); a += __shfl_xor(a, 2);
        if (part == 0) lg[e] = a;
        __syncthreads();
        if (tt < 4) {   // lanes 0..3 redo top-2 + weights for this row
            const int q = tt;
            float v1 = -3.4e38f, v2 = -3.4e38f; int e1 = 1 << 30, e2 = 1 << 30;
            float sl = 0.0f, mxl = -3.4e38f;
            float Lr[16];
            #pragma unroll
            for (int i = 0; i < 16; ++i) {
                float v = Lr[i] = lg[q * 16 + i]; int ee = q * 16 + i;
                if      (gt_(v, ee, v1, e1)) { v2 = v1; e2 = e1; v1 = v; e1 = ee; }
                else if (gt_(v, ee, v2, e2)) { v2 = v; e2 = ee; }
                mxl = fmaxf(mxl, v);
            }
            #pragma unroll
            for (int m = 1; m <= 2; m <<= 1) {
                float o1 = __shfl_xor(v1, m), o2 = __shfl_xor(v2, m);
                int  oe1 = __shfl_xor(e1, m), oe2 = __shfl_xor(e2, m);
                float n1, n2; int m1, m2;
                if (gt_(v1, e1, o1, oe1)) {
                    n1 = v1; m1 = e1;
                    if (gt_(v2, e2, o1, oe1)) { n2 = v2; m2 = e2; } else { n2 = o1; m2 = oe1; }
                } else {
                    n1 = o1; m1 = oe1;
                    if (gt_(o2, oe2, v1, e1)) { n2 = o2; m2 = oe2; } else { n2 = v1; m2 = e1; }
                }
                v1 = n1; e1 = m1; v2 = n2; e2 = m2;
            }
            float s = 0.0f;
            #pragma unroll
            for (int i = 0; i < 16; ++i) s += expf(Lr[i] - v1);
            s += __shfl_xor(s, 1); s += __shfl_xor(s, 2);
            if (q == 0) {
                const float invS = 1.0f / s;
                const float p1 = invS, p2 = expf(v2 - v1) * invS;
                const float dn = p1 + p2 + EPSF;
                out[2 * row]                 = p1 / dn;
                out[2 * row + 1]             = p2 / dn;
                out[2 * NROWS + 2 * row]     = (float)e1;
                out[2 * NROWS + 2 * row + 1] = (float)e2;
            }
        }
        __syncthreads();
    }
}

extern "C" void kernel_launch(void* const* d_in, const int* in_sizes, int n_in,
                              void* d_out, int out_size, void* d_ws, size_t ws_size,
                              hipStream_t stream)
{
    const float* x  = (const float*)d_in[0];
    const float* gw = (const float*)d_in[1];
    float* out      = (float*)d_out;

    float* meanacc = (float*)d_ws;                       // 64 f32
    int*   cnt     = (int*)((char*)d_ws + 256);
    int*   list    = (int*)((char*)d_ws + 512);
    int cap = 0;
    if (ws_size >= 1024)
        cap = (int)((ws_size - 512) / sizeof(int));
    if (cap > CAPMAX) cap = CAPMAX;

    const size_t lds_bytes = 2u * 64u * LSTR * sizeof(unsigned short); // 67584

    hipLaunchKernelGGL(prep_kernel, dim3(1), dim3(128), 0, stream, meanacc, cnt, cap);
    hipLaunchKernelGGL(moe_mfma, dim3(NROWS / BM), dim3(256), lds_bytes, stream,
                       x, gw, out, meanacc, cnt, list, cap);
    hipLaunchKernelGGL(finalize_kernel, dim3(65), dim3(256), 0, stream,
                       x, gw, out, meanacc, cnt, list, cap);
}

// Round 6
// 107.725 us; speedup vs baseline: 1.3312x; 1.3312x over previous
//
#include <hip/hip_runtime.h>
#include <math.h>

#define NROWS 32768
#define DDIM  1024
#define NEXP  64
#define TAU   2e-4f
#define EPSF  1e-9f
#define CAPMAX 8192

typedef __attribute__((ext_vector_type(8)))  short  short8;
typedef __attribute__((ext_vector_type(16))) float  f32x16;

// stable greater-than: value desc, index asc on ties (matches lax.top_k)
__device__ __forceinline__ bool gt_(float a, int ea, float b, int eb)
{ return a > b || (a == b && ea < eb); }

// split f into bf16 hi (RN) + bf16 lo (RN of residual)
__device__ __forceinline__ void cvt_hl(float f, unsigned short& h, unsigned short& l)
{
    unsigned u  = __float_as_uint(f);
    unsigned hu = (u + 0x7FFFu + ((u >> 16) & 1u)) & 0xFFFF0000u;
    h = (unsigned short)(hu >> 16);
    float r = f - __uint_as_float(hu);
    unsigned v = __float_as_uint(r);
    l = (unsigned short)((v + 0x7FFFu + ((v >> 16) & 1u)) >> 16);
}

// ---------------------------------------------------------------------------
// Pack gate_w ONCE into per-lane MFMA B-fragment order, bf16 hi+lo:
// wp[((kc*2+g)*2+pr)*512 + lane*8 + j] = bf16_pr( w[g*32+(lane&31)][kc*16+(lane>>5)*8+j] )
// (fragment lane-mapping HW-verified by R5's passing kernel)
// ---------------------------------------------------------------------------
__global__ void wpack_kernel(const float* __restrict__ gw,
                             unsigned short* __restrict__ wp,
                             int* __restrict__ cnt)
{
    if (blockIdx.x == 0 && threadIdx.x == 0) *cnt = 0;
    const int kc = blockIdx.x;              // 0..63
    const int t  = threadIdx.x;             // 256
    const int lane = t & 63, g = (t >> 6) & 1, pr = t >> 7;
    const int e = g * 32 + (lane & 31);
    const int k = kc * 16 + (lane >> 5) * 8;
    float4 f0 = *reinterpret_cast<const float4*>(gw + (size_t)e * DDIM + k);
    float4 f1 = *reinterpret_cast<const float4*>(gw + (size_t)e * DDIM + k + 4);
    float f[8] = {f0.x, f0.y, f0.z, f0.w, f1.x, f1.y, f1.z, f1.w};
    short8 o;
    #pragma unroll
    for (int j = 0; j < 8; ++j) {
        unsigned short hh, ll;
        cvt_hl(f[j], hh, ll);
        o[j] = pr ? (short)ll : (short)hh;
    }
    *reinterpret_cast<short8*>(wp + ((size_t)((kc * 2 + g) * 2 + pr) * 64 + lane) * 8) = o;
}

// ---------------------------------------------------------------------------
// Main: barrier-free streaming GEMM. grid 1024 x 256 thr; block = 32 rows,
// wave = one K-quarter (16 kc of 16 fp32 k). Per kc: load x-frag straight
// from global (2 float4/lane), convert to bf16 hi/lo in-register, load 4
// pre-packed B-frags (coalesced short8), 6 MFMAs (xl*wl term dropped,
// ~3e-7 on logits). One-chunk software prefetch; NO barriers until the
// end-of-kernel 4-way split-K LDS tree.
// ---------------------------------------------------------------------------
__global__ __launch_bounds__(256, 3) void moe_main(
    const float* __restrict__ x, const unsigned short* __restrict__ wp,
    float* __restrict__ out, float* __restrict__ auxpart,
    int* __restrict__ cnt, int* __restrict__ list, int cap)
{
    __shared__ float red[2][16][2][64];     // 16 KB reduce regions

    const int t = threadIdx.x;
    const int wave = t >> 6, lane = t & 63;
    const int l31 = lane & 31, l5 = lane >> 5;
    const int row0 = blockIdx.x * 32;

    f32x16 acc0, acc1;
    #pragma unroll
    for (int r = 0; r < 16; ++r) { acc0[r] = 0.0f; acc1[r] = 0.0f; }

    const float* xq = x + (size_t)(row0 + l31) * DDIM + l5 * 8 + wave * 256;
    const unsigned short* wq = wp + (size_t)lane * 8 + (size_t)wave * 32768;

    float4 xa[2], xb[2];
    short8 bh0[2], bl0[2], bh1[2], bl1[2];

    xa[0]  = *reinterpret_cast<const float4*>(xq);
    xb[0]  = *reinterpret_cast<const float4*>(xq + 4);
    bh0[0] = *reinterpret_cast<const short8*>(wq);
    bl0[0] = *reinterpret_cast<const short8*>(wq + 512);
    bh1[0] = *reinterpret_cast<const short8*>(wq + 1024);
    bl1[0] = *reinterpret_cast<const short8*>(wq + 1536);

    #pragma unroll
    for (int i = 0; i < 16; ++i) {
        const int cur = i & 1, nxt = cur ^ 1;
        if (i < 15) {                       // prefetch next kc
            const int xo = (i + 1) * 16;
            const int wo = (i + 1) * 2048;
            xa[nxt]  = *reinterpret_cast<const float4*>(xq + xo);
            xb[nxt]  = *reinterpret_cast<const float4*>(xq + xo + 4);
            bh0[nxt] = *reinterpret_cast<const short8*>(wq + wo);
            bl0[nxt] = *reinterpret_cast<const short8*>(wq + wo + 512);
            bh1[nxt] = *reinterpret_cast<const short8*>(wq + wo + 1024);
            bl1[nxt] = *reinterpret_cast<const short8*>(wq + wo + 1536);
        }
        float f[8] = {xa[cur].x, xa[cur].y, xa[cur].z, xa[cur].w,
                      xb[cur].x, xb[cur].y, xb[cur].z, xb[cur].w};
        short8 ah, al;
        #pragma unroll
        for (int j = 0; j < 8; ++j) {
            unsigned short hh, ll;
            cvt_hl(f[j], hh, ll);
            ah[j] = (short)hh; al[j] = (short)ll;
        }
        acc0 = __builtin_amdgcn_mfma_f32_32x32x16_bf16(ah, bh0[cur], acc0, 0, 0, 0);
        acc1 = __builtin_amdgcn_mfma_f32_32x32x16_bf16(ah, bh1[cur], acc1, 0, 0, 0);
        acc0 = __builtin_amdgcn_mfma_f32_32x32x16_bf16(al, bh0[cur], acc0, 0, 0, 0);
        acc1 = __builtin_amdgcn_mfma_f32_32x32x16_bf16(al, bh1[cur], acc1, 0, 0, 0);
        acc0 = __builtin_amdgcn_mfma_f32_32x32x16_bf16(ah, bl0[cur], acc0, 0, 0, 0);
        acc1 = __builtin_amdgcn_mfma_f32_32x32x16_bf16(ah, bl1[cur], acc1, 0, 0, 0);
    }

    // ---- 4-way split-K reduction (tree through LDS) -----------------------
    __syncthreads();
    if (wave >= 2) {
        #pragma unroll
        for (int r = 0; r < 16; ++r) {
            red[wave - 2][r][0][lane] = acc0[r];
            red[wave - 2][r][1][lane] = acc1[r];
        }
    }
    __syncthreads();
    if (wave < 2) {
        #pragma unroll
        for (int r = 0; r < 16; ++r) {
            acc0[r] += red[wave][r][0][lane];
            acc1[r] += red[wave][r][1][lane];
        }
    }
    __syncthreads();
    if (wave == 1) {
        #pragma unroll
        for (int r = 0; r < 16; ++r) {
            red[0][r][0][lane] = acc0[r];
            red[0][r][1][lane] = acc1[r];
        }
    }
    __syncthreads();
    if (wave != 0) return;                  // all barriers complete
    #pragma unroll
    for (int r = 0; r < 16; ++r) {
        acc0[r] += red[0][r][0][lane];
        acc1[r] += red[0][r][1][lane];
    }

    // ---- epilogue (wave 0): logits -> LDS, 2 lanes per row ----------------
    float* lgs = &red[0][0][0][0];          // reuse as [32][72] f32
    #pragma unroll
    for (int r = 0; r < 16; ++r) {          // C layout: col=lane&31, row=(r&3)+8*(r>>2)+4*l5
        const int row = (r & 3) + 8 * (r >> 2) + 4 * l5;
        lgs[row * 72 + l31]      = acc0[r];
        lgs[row * 72 + 32 + l31] = acc1[r];
    }
    const int rr = lane >> 1, h = lane & 1;
    float L[32];
    #pragma unroll
    for (int i = 0; i < 8; ++i) {
        float4 v = *reinterpret_cast<const float4*>(lgs + rr * 72 + h * 32 + i * 4);
        L[4*i] = v.x; L[4*i+1] = v.y; L[4*i+2] = v.z; L[4*i+3] = v.w;
    }
    float v1 = -3.4e38f, v2 = -3.4e38f, v3 = -3.4e38f;
    int   e1 = 1 << 30,  e2 = 1 << 30,  e3 = 1 << 30;
    #pragma unroll
    for (int i = 0; i < 32; ++i) {
        float v = L[i]; int e = h * 32 + i;
        if      (gt_(v, e, v1, e1)) { v3=v2; e3=e2; v2=v1; e2=e1; v1=v; e1=e; }
        else if (gt_(v, e, v2, e2)) { v3=v2; e3=e2; v2=v; e2=e; }
        else if (gt_(v, e, v3, e3)) { v3=v; e3=e; }
    }
    {   // merge the row's two lanes (xor 1), stable 3-way
        float o1 = __shfl_xor(v1, 1), o2 = __shfl_xor(v2, 1), o3 = __shfl_xor(v3, 1);
        int  oe1 = __shfl_xor(e1, 1), oe2 = __shfl_xor(e2, 1), oe3 = __shfl_xor(e3, 1);
        float n1, n2, n3; int m1, m2, m3;
        if (gt_(v1, e1, o1, oe1)) {
            n1 = v1; m1 = e1;
            if (gt_(v2, e2, o1, oe1)) {
                n2 = v2; m2 = e2;
                if (gt_(v3, e3, o1, oe1)) { n3 = v3; m3 = e3; } else { n3 = o1; m3 = oe1; }
            } else {
                n2 = o1; m2 = oe1;
                if (gt_(v2, e2, o2, oe2)) { n3 = v2; m3 = e2; } else { n3 = o2; m3 = oe2; }
            }
        } else {
            n1 = o1; m1 = oe1;
            if (gt_(o2, oe2, v1, e1)) {
                n2 = o2; m2 = oe2;
                if (gt_(o3, oe3, v1, e1)) { n3 = o3; m3 = oe3; } else { n3 = v1; m3 = e1; }
            } else {
                n2 = v1; m2 = e1;
                if (gt_(o2, oe2, v2, e2)) { n3 = o2; m3 = oe2; } else { n3 = v2; m3 = e2; }
            }
        }
        v1 = n1; e1 = m1; v2 = n2; e2 = m2; v3 = n3; e3 = m3;
    }
    float S = 0.0f;
    #pragma unroll
    for (int i = 0; i < 32; ++i) { L[i] = expf(L[i] - v1); S += L[i]; }
    S += __shfl_xor(S, 1);
    const float invS = 1.0f / S;
    #pragma unroll
    for (int i = 0; i < 32; ++i) L[i] *= invS;
    // cross-row butterfly (bit0 = h preserved): lanes 0/1 end with expert sums
    #pragma unroll
    for (int m = 2; m <= 32; m <<= 1)
        #pragma unroll
        for (int i = 0; i < 32; ++i) L[i] += __shfl_xor(L[i], m);
    if (lane < 2) {
        #pragma unroll
        for (int i = 0; i < 32; ++i)
            auxpart[(size_t)blockIdx.x * 64 + h * 32 + i] = L[i];
    }
    if (h == 0) {
        const float p1 = invS;                    // exp(v1-v1)*invS
        const float p2 = expf(v2 - v1) * invS;
        const float dn = p1 + p2 + EPSF;
        const int r = row0 + rr;
        out[2 * r]                 = p1 / dn;
        out[2 * r + 1]             = p2 / dn;
        out[2 * NROWS + 2 * r]     = (float)e1;
        out[2 * NROWS + 2 * r + 1] = (float)e2;
        if (cap > 0 && (v1 - v2 < TAU || v2 - v3 < TAU)) {
            int pos = atomicAdd(cnt, 1);
            if (pos < cap) list[pos] = r;
        }
    }
}

// ---------------------------------------------------------------------------
// Finalize: block 0 sums aux partials -> aux loss; blocks 1..64 repair
// flagged rows with exact fp32 logits.
// ---------------------------------------------------------------------------
__global__ __launch_bounds__(256) void finalize_kernel(
    const float* __restrict__ x, const float* __restrict__ gw,
    float* __restrict__ out, const float* __restrict__ auxpart,
    const int* __restrict__ cnt, const int* __restrict__ list, int cap)
{
    if (blockIdx.x == 0) {
        __shared__ float part[4][64];
        const int tt = threadIdx.x;
        const int e = tt & 63, p = tt >> 6;
        float s = 0.0f;
        for (int b = p; b < NROWS / 32; b += 4)
            s += auxpart[(size_t)b * 64 + e];
        part[p][e] = s;
        __syncthreads();
        if (tt < 64) {
            float m = (part[0][tt] + part[1][tt] + part[2][tt] + part[3][tt])
                      * (1.0f / (float)NROWS);
            float v = m * logf(m + EPSF);
            #pragma unroll
            for (int k = 1; k <= 32; k <<= 1) v += __shfl_xor(v, k);
            if (tt == 0) out[4 * NROWS] = v;
        }
        return;
    }
    __shared__ float lg[64];
    const int n = (cap > 0) ? min(*cnt, cap) : 0;
    const int tt = threadIdx.x, e = tt >> 2, part = tt & 3;
    for (int j = (int)blockIdx.x - 1; j < n; j += 64) {
        const int row = list[j];
        const float* xr = x  + (size_t)row * DDIM + part * 256;
        const float* wr = gw + (size_t)e   * DDIM + part * 256;
        float a = 0.0f;
        #pragma unroll 8
        for (int kk = 0; kk < 64; ++kk) {
            float4 xv = *reinterpret_cast<const float4*>(xr + kk * 4);
            float4 wv = *reinterpret_cast<const float4*>(wr + kk * 4);
            a += xv.x * wv.x + xv.y * wv.y + xv.z * wv.z + xv.w * wv.w;
        }
        a += __shfl_xor(a, 1); a += __shfl_xor(a, 2);
        if (part == 0) lg[e] = a;
        __syncthreads();
        if (tt < 4) {
            const int q = tt;
            float v1 = -3.4e38f, v2 = -3.4e38f; int e1 = 1 << 30, e2 = 1 << 30;
            float Lr[16];
            #pragma unroll
            for (int i = 0; i < 16; ++i) {
                float v = Lr[i] = lg[q * 16 + i]; int ee = q * 16 + i;
                if      (gt_(v, ee, v1, e1)) { v2 = v1; e2 = e1; v1 = v; e1 = ee; }
                else if (gt_(v, ee, v2, e2)) { v2 = v; e2 = ee; }
            }
            #pragma unroll
            for (int m = 1; m <= 2; m <<= 1) {
                float o1 = __shfl_xor(v1, m), o2 = __shfl_xor(v2, m);
                int  oe1 = __shfl_xor(e1, m), oe2 = __shfl_xor(e2, m);
                float n1, n2; int m1, m2;
                if (gt_(v1, e1, o1, oe1)) {
                    n1 = v1; m1 = e1;
                    if (gt_(v2, e2, o1, oe1)) { n2 = v2; m2 = e2; } else { n2 = o1; m2 = oe1; }
                } else {
                    n1 = o1; m1 = oe1;
                    if (gt_(o2, oe2, v1, e1)) { n2 = o2; m2 = oe2; } else { n2 = v1; m2 = e1; }
                }
                v1 = n1; e1 = m1; v2 = n2; e2 = m2;
            }
            float s = 0.0f;
            #pragma unroll
            for (int i = 0; i < 16; ++i) s += expf(Lr[i] - v1);
            s += __shfl_xor(s, 1); s += __shfl_xor(s, 2);
            if (q == 0) {
                const float invS = 1.0f / s;
                const float p1 = invS, p2 = expf(v2 - v1) * invS;
                const float dn = p1 + p2 + EPSF;
                out[2 * row]                 = p1 / dn;
                out[2 * row + 1]             = p2 / dn;
                out[2 * NROWS + 2 * row]     = (float)e1;
                out[2 * NROWS + 2 * row + 1] = (float)e2;
            }
        }
        __syncthreads();
    }
}

extern "C" void kernel_launch(void* const* d_in, const int* in_sizes, int n_in,
                              void* d_out, int out_size, void* d_ws, size_t ws_size,
                              hipStream_t stream)
{
    const float* x  = (const float*)d_in[0];
    const float* gw = (const float*)d_in[1];
    float* out      = (float*)d_out;

    // d_ws layout: [wp 256KB][auxpart 256KB][cnt 4B pad->256][list ...]
    unsigned short* wp = (unsigned short*)d_ws;
    float* auxpart = (float*)((char*)d_ws + 262144);
    int*   cnt     = (int*)((char*)d_ws + 524288);
    int*   list    = (int*)((char*)d_ws + 524544);
    int cap = 0;
    if (ws_size >= 524544 + 4096) {
        size_t avail = (ws_size - 524544) / sizeof(int);
        cap = (avail > CAPMAX) ? CAPMAX : (int)avail;
    }

    hipLaunchKernelGGL(wpack_kernel, dim3(64), dim3(256), 0, stream, gw, wp, cnt);
    hipLaunchKernelGGL(moe_main, dim3(NROWS / 32), dim3(256), 0, stream,
                       x, wp, out, auxpart, cnt, list, cap);
    hipLaunchKernelGGL(finalize_kernel, dim3(65), dim3(256), 0, stream,
                       x, gw, out, auxpart, cnt, list, cap);
}

// Round 7
// 104.774 us; speedup vs baseline: 1.3687x; 1.0282x over previous
//
#include <hip/hip_runtime.h>
#include <math.h>

#define NROWS 32768
#define DDIM  1024
#define NEXP  64
#define TAU   2e-4f
#define EPSF  1e-9f
#define CAPMAX 8192
#define NSHARD 8

typedef __attribute__((ext_vector_type(8)))  short  short8;
typedef __attribute__((ext_vector_type(16))) float  f32x16;
typedef __attribute__((address_space(3))) unsigned int       lds_u32;
typedef __attribute__((address_space(1))) const unsigned int g_u32;

// stable greater-than: value desc, index asc on ties (matches lax.top_k)
__device__ __forceinline__ bool gt_(float a, int ea, float b, int eb)
{ return a > b || (a == b && ea < eb); }

// split f into bf16 hi (RN) + bf16 lo (RN of residual)
__device__ __forceinline__ void cvt_hl(float f, unsigned short& h, unsigned short& l)
{
    unsigned u  = __float_as_uint(f);
    unsigned hu = (u + 0x7FFFu + ((u >> 16) & 1u)) & 0xFFFF0000u;
    h = (unsigned short)(hu >> 16);
    float r = f - __uint_as_float(hu);
    unsigned v = __float_as_uint(r);
    l = (unsigned short)((v + 0x7FFFu + ((v >> 16) & 1u)) >> 16);
}

// ---------------------------------------------------------------------------
// Pack gate_w ONCE into per-lane MFMA B-fragment order, bf16 hi+lo
// (fragment lane-mapping HW-verified R5/R6). Block 0 also zeroes the aux
// shards + repair counter.
// ---------------------------------------------------------------------------
__global__ void wpack_kernel(const float* __restrict__ gw,
                             unsigned short* __restrict__ wp,
                             float* __restrict__ shard,
                             int* __restrict__ cnt)
{
    if (blockIdx.x == 0) {
        shard[threadIdx.x]       = 0.0f;
        shard[256 + threadIdx.x] = 0.0f;
        if (threadIdx.x == 0) *cnt = 0;
    }
    const int kc = blockIdx.x;              // 0..63
    const int t  = threadIdx.x;             // 256
    const int lane = t & 63, g = (t >> 6) & 1, pr = t >> 7;
    const int e = g * 32 + (lane & 31);
    const int k = kc * 16 + (lane >> 5) * 8;
    float4 f0 = *reinterpret_cast<const float4*>(gw + (size_t)e * DDIM + k);
    float4 f1 = *reinterpret_cast<const float4*>(gw + (size_t)e * DDIM + k + 4);
    float f[8] = {f0.x, f0.y, f0.z, f0.w, f1.x, f1.y, f1.z, f1.w};
    short8 o;
    #pragma unroll
    for (int j = 0; j < 8; ++j) {
        unsigned short hh, ll;
        cvt_hl(f[j], hh, ll);
        o[j] = pr ? (short)ll : (short)hh;
    }
    *reinterpret_cast<short8*>(wp + ((size_t)((kc * 2 + g) * 2 + pr) * 64 + lane) * 8) = o;
}

// ---------------------------------------------------------------------------
// Main: grid 1024 x 256 thr, 32 rows/block, 16 chunks of 64 fp32 k.
// x staged COALESCED into dbuf LDS tiles via global_load_lds(16B) with the
// both-sides XOR swizzle (byte ^= ((row&7)<<5)): linear LDS dest +
// inverse-swizzled global source + swizzled ds_read -> conflict-light reads.
// Per chunk, wave handles 16 k's (kc = c*4+wave): ds_read 32B -> cvt to
// bf16 hi/lo -> 6 MFMAs with L2-prefetched packed B-frags. One barrier per
// chunk. 4-way split-K LDS tree; R6-verified epilogue; 8-sharded atomic aux.
// ---------------------------------------------------------------------------
__global__ __launch_bounds__(256, 4) void moe_main(
    const float* __restrict__ x, const unsigned short* __restrict__ wp,
    float* __restrict__ out, float* __restrict__ shard,
    int* __restrict__ cnt, int* __restrict__ list, int cap)
{
    extern __shared__ float smem[];         // 16 KB: 2 x 8 KB x-tile buffers

    const int t = threadIdx.x;
    const int wave = t >> 6, lane = t & 63;
    const int l31 = lane & 31, l5 = lane >> 5;
    const int row0 = blockIdx.x * 32;

    // staging map: linear dest byte d -> holds logical byte d^((d>>8&7)<<5)
    int srow[2], scol[2];
    #pragma unroll
    for (int q = 0; q < 2; ++q) {
        int d   = ((wave * 2 + q) * 64 + lane) * 16;
        int swz = d ^ (((d >> 8) & 7) << 5);
        srow[q] = swz >> 8;                 // tile row 0..31
        scol[q] = (swz & 255) >> 2;         // float col 0..63
    }

    f32x16 acc0, acc1;
    #pragma unroll
    for (int r = 0; r < 16; ++r) { acc0[r] = 0.0f; acc1[r] = 0.0f; }

    const unsigned short* wq = wp + (size_t)lane * 8;

    #define STAGE(buf, c)                                                        \
        {                                                                        \
            const float* base_ = x + (size_t)row0 * DDIM + (c) * 64;             \
            _Pragma("unroll")                                                    \
            for (int q = 0; q < 2; ++q) {                                        \
                const float* src_ = base_ + (size_t)srow[q] * DDIM + scol[q];    \
                lds_u32* dst_ = (lds_u32*)(smem + (buf) * 2048 + (wave * 2 + q) * 256); \
                __builtin_amdgcn_global_load_lds((g_u32*)src_, dst_, 16, 0, 0);  \
            }                                                                    \
        }

    // prologue: stage chunk 0, prefetch w for chunk 0 (this wave's kc = wave)
    STAGE(0, 0);
    short8 bh0c, bl0c, bh1c, bl1c, bh0n, bl0n, bh1n, bl1n;
    {
        const unsigned short* w0 = wq + (size_t)wave * 2048;
        bh0c = *reinterpret_cast<const short8*>(w0);
        bl0c = *reinterpret_cast<const short8*>(w0 + 512);
        bh1c = *reinterpret_cast<const short8*>(w0 + 1024);
        bl1c = *reinterpret_cast<const short8*>(w0 + 1536);
    }
    __syncthreads();

    for (int c = 0; c < 16; ++c) {
        const int buf = c & 1;
        if (c < 15) {
            STAGE(buf ^ 1, c + 1);
            const unsigned short* wn = wq + (size_t)((c + 1) * 4 + wave) * 2048;
            bh0n = *reinterpret_cast<const short8*>(wn);
            bl0n = *reinterpret_cast<const short8*>(wn + 512);
            bh1n = *reinterpret_cast<const short8*>(wn + 1024);
            bl1n = *reinterpret_cast<const short8*>(wn + 1536);
        }
        // A-frag: swizzled 32B read (row l31, float cols wave*16+l5*8 ..+8)
        int lb = l31 * 256 + wave * 64 + l5 * 32;
        lb ^= ((l31 & 7) << 5);
        const float* ap = reinterpret_cast<const float*>(
            reinterpret_cast<const char*>(smem + buf * 2048) + lb);
        float4 f0 = *reinterpret_cast<const float4*>(ap);
        float4 f1 = *reinterpret_cast<const float4*>(ap + 4);
        float f[8] = {f0.x, f0.y, f0.z, f0.w, f1.x, f1.y, f1.z, f1.w};
        short8 ah, al;
        #pragma unroll
        for (int j = 0; j < 8; ++j) {
            unsigned short hh, ll;
            cvt_hl(f[j], hh, ll);
            ah[j] = (short)hh; al[j] = (short)ll;
        }
        acc0 = __builtin_amdgcn_mfma_f32_32x32x16_bf16(ah, bh0c, acc0, 0, 0, 0);
        acc1 = __builtin_amdgcn_mfma_f32_32x32x16_bf16(ah, bh1c, acc1, 0, 0, 0);
        acc0 = __builtin_amdgcn_mfma_f32_32x32x16_bf16(al, bh0c, acc0, 0, 0, 0);
        acc1 = __builtin_amdgcn_mfma_f32_32x32x16_bf16(al, bh1c, acc1, 0, 0, 0);
        acc0 = __builtin_amdgcn_mfma_f32_32x32x16_bf16(ah, bl0c, acc0, 0, 0, 0);
        acc1 = __builtin_amdgcn_mfma_f32_32x32x16_bf16(ah, bl1c, acc1, 0, 0, 0);
        bh0c = bh0n; bl0c = bl0n; bh1c = bh1n; bl1c = bl1n;
        __syncthreads();
    }
    #undef STAGE

    // ---- 4-way split-K reduction (tree through LDS, reuses x-tile space) --
    float* red = smem;                      // [2][16][2][64] floats = 16 KB
    if (wave >= 2) {
        #pragma unroll
        for (int r = 0; r < 16; ++r) {
            red[(((wave - 2) * 16 + r) * 2 + 0) * 64 + lane] = acc0[r];
            red[(((wave - 2) * 16 + r) * 2 + 1) * 64 + lane] = acc1[r];
        }
    }
    __syncthreads();
    if (wave < 2) {
        #pragma unroll
        for (int r = 0; r < 16; ++r) {
            acc0[r] += red[((wave * 16 + r) * 2 + 0) * 64 + lane];
            acc1[r] += red[((wave * 16 + r) * 2 + 1) * 64 + lane];
        }
    }
    __syncthreads();
    if (wave == 1) {
        #pragma unroll
        for (int r = 0; r < 16; ++r) {
            red[(r * 2 + 0) * 64 + lane] = acc0[r];
            red[(r * 2 + 1) * 64 + lane] = acc1[r];
        }
    }
    __syncthreads();
    if (wave != 0) return;                  // all barriers complete
    #pragma unroll
    for (int r = 0; r < 16; ++r) {
        acc0[r] += red[(r * 2 + 0) * 64 + lane];
        acc1[r] += red[(r * 2 + 1) * 64 + lane];
    }

    // ---- epilogue (wave 0 only; verified R6) ------------------------------
    float* lgs = smem;                      // [32][72] f32
    #pragma unroll
    for (int r = 0; r < 16; ++r) {          // C layout: col=lane&31, row=(r&3)+8*(r>>2)+4*l5
        const int row = (r & 3) + 8 * (r >> 2) + 4 * l5;
        lgs[row * 72 + l31]      = acc0[r];
        lgs[row * 72 + 32 + l31] = acc1[r];
    }
    const int rr = lane >> 1, h = lane & 1;
    float L[32];
    #pragma unroll
    for (int i = 0; i < 8; ++i) {
        float4 v = *reinterpret_cast<const float4*>(lgs + rr * 72 + h * 32 + i * 4);
        L[4*i] = v.x; L[4*i+1] = v.y; L[4*i+2] = v.z; L[4*i+3] = v.w;
    }
    float v1 = -3.4e38f, v2 = -3.4e38f, v3 = -3.4e38f;
    int   e1 = 1 << 30,  e2 = 1 << 30,  e3 = 1 << 30;
    #pragma unroll
    for (int i = 0; i < 32; ++i) {
        float v = L[i]; int e = h * 32 + i;
        if      (gt_(v, e, v1, e1)) { v3=v2; e3=e2; v2=v1; e2=e1; v1=v; e1=e; }
        else if (gt_(v, e, v2, e2)) { v3=v2; e3=e2; v2=v; e2=e; }
        else if (gt_(v, e, v3, e3)) { v3=v; e3=e; }
    }
    {   // merge the row's two lanes (xor 1), stable 3-way
        float o1 = __shfl_xor(v1, 1), o2 = __shfl_xor(v2, 1), o3 = __shfl_xor(v3, 1);
        int  oe1 = __shfl_xor(e1, 1), oe2 = __shfl_xor(e2, 1), oe3 = __shfl_xor(e3, 1);
        float n1, n2, n3; int m1, m2, m3;
        if (gt_(v1, e1, o1, oe1)) {
            n1 = v1; m1 = e1;
            if (gt_(v2, e2, o1, oe1)) {
                n2 = v2; m2 = e2;
                if (gt_(v3, e3, o1, oe1)) { n3 = v3; m3 = e3; } else { n3 = o1; m3 = oe1; }
            } else {
                n2 = o1; m2 = oe1;
                if (gt_(v2, e2, o2, oe2)) { n3 = v2; m3 = e2; } else { n3 = o2; m3 = oe2; }
            }
        } else {
            n1 = o1; m1 = oe1;
            if (gt_(o2, oe2, v1, e1)) {
                n2 = o2; m2 = oe2;
                if (gt_(o3, oe3, v1, e1)) { n3 = o3; m3 = oe3; } else { n3 = v1; m3 = e1; }
            } else {
                n2 = v1; m2 = e1;
                if (gt_(o2, oe2, v2, e2)) { n3 = o2; m3 = oe2; } else { n3 = v2; m3 = e2; }
            }
        }
        v1 = n1; e1 = m1; v2 = n2; e2 = m2; v3 = n3; e3 = m3;
    }
    float S = 0.0f;
    #pragma unroll
    for (int i = 0; i < 32; ++i) { L[i] = expf(L[i] - v1); S += L[i]; }
    S += __shfl_xor(S, 1);
    const float invS = 1.0f / S;
    #pragma unroll
    for (int i = 0; i < 32; ++i) L[i] *= invS;
    // cross-row butterfly (bit0 = h preserved): lanes 0/1 hold expert sums
    #pragma unroll
    for (int m = 2; m <= 32; m <<= 1)
        #pragma unroll
        for (int i = 0; i < 32; ++i) L[i] += __shfl_xor(L[i], m);
    if (lane < 2) {
        float* sh = shard + (blockIdx.x & (NSHARD - 1)) * 64 + h * 32;
        #pragma unroll
        for (int i = 0; i < 32; ++i) atomicAdd(&sh[i], L[i]);
    }
    if (h == 0) {
        const float p1 = invS;                    // exp(v1-v1)*invS
        const float p2 = expf(v2 - v1) * invS;
        const float dn = p1 + p2 + EPSF;
        const int r = row0 + rr;
        out[2 * r]                 = p1 / dn;
        out[2 * r + 1]             = p2 / dn;
        out[2 * NROWS + 2 * r]     = (float)e1;
        out[2 * NROWS + 2 * r + 1] = (float)e2;
        if (cap > 0 && (v1 - v2 < TAU || v2 - v3 < TAU)) {
            int pos = atomicAdd(cnt, 1);
            if (pos < cap) list[pos] = r;
        }
    }
}

// ---------------------------------------------------------------------------
// Finalize: block 0 sums 8 aux shards -> aux loss; blocks 1..64 repair
// flagged rows with exact fp32 logits.
// ---------------------------------------------------------------------------
__global__ __launch_bounds__(256) void finalize_kernel(
    const float* __restrict__ x, const float* __restrict__ gw,
    float* __restrict__ out, const float* __restrict__ shard,
    const int* __restrict__ cnt, const int* __restrict__ list, int cap)
{
    if (blockIdx.x == 0) {
        const int tt = threadIdx.x;
        if (tt < 64) {
            float m = 0.0f;
            #pragma unroll
            for (int s = 0; s < NSHARD; ++s) m += shard[s * 64 + tt];
            m *= (1.0f / (float)NROWS);
            float v = m * logf(m + EPSF);
            #pragma unroll
            for (int k = 1; k <= 32; k <<= 1) v += __shfl_xor(v, k);
            if (tt == 0) out[4 * NROWS] = v;
        }
        return;
    }
    __shared__ float lg[64];
    const int n = (cap > 0) ? min(*cnt, cap) : 0;
    const int tt = threadIdx.x, e = tt >> 2, part = tt & 3;
    for (int j = (int)blockIdx.x - 1; j < n; j += 64) {
        const int row = list[j];
        const float* xr = x  + (size_t)row * DDIM + part * 256;
        const float* wr = gw + (size_t)e   * DDIM + part * 256;
        float a = 0.0f;
        #pragma unroll 8
        for (int kk = 0; kk < 64; ++kk) {
            float4 xv = *reinterpret_cast<const float4*>(xr + kk * 4);
            float4 wv = *reinterpret_cast<const float4*>(wr + kk * 4);
            a += xv.x * wv.x + xv.y * wv.y + xv.z * wv.z + xv.w * wv.w;
        }
        a += __shfl_xor(a, 1); a += __shfl_xor(a, 2);
        if (part == 0) lg[e] = a;
        __syncthreads();
        if (tt < 4) {
            const int q = tt;
            float v1 = -3.4e38f, v2 = -3.4e38f; int e1 = 1 << 30, e2 = 1 << 30;
            float Lr[16];
            #pragma unroll
            for (int i = 0; i < 16; ++i) {
                float v = Lr[i] = lg[q * 16 + i]; int ee = q * 16 + i;
                if      (gt_(v, ee, v1, e1)) { v2 = v1; e2 = e1; v1 = v; e1 = ee; }
                else if (gt_(v, ee, v2, e2)) { v2 = v; e2 = ee; }
            }
            #pragma unroll
            for (int m = 1; m <= 2; m <<= 1) {
                float o1 = __shfl_xor(v1, m), o2 = __shfl_xor(v2, m);
                int  oe1 = __shfl_xor(e1, m), oe2 = __shfl_xor(e2, m);
                float n1, n2; int m1, m2;
                if (gt_(v1, e1, o1, oe1)) {
                    n1 = v1; m1 = e1;
                    if (gt_(v2, e2, o1, oe1)) { n2 = v2; m2 = e2; } else { n2 = o1; m2 = oe1; }
                } else {
                    n1 = o1; m1 = oe1;
                    if (gt_(o2, oe2, v1, e1)) { n2 = o2; m2 = oe2; } else { n2 = v1; m2 = e1; }
                }
                v1 = n1; e1 = m1; v2 = n2; e2 = m2;
            }
            float s = 0.0f;
            #pragma unroll
            for (int i = 0; i < 16; ++i) s += expf(Lr[i] - v1);
            s += __shfl_xor(s, 1); s += __shfl_xor(s, 2);
            if (q == 0) {
                const float invS = 1.0f / s;
                const float p1 = invS, p2 = expf(v2 - v1) * invS;
                const float dn = p1 + p2 + EPSF;
                out[2 * row]                 = p1 / dn;
                out[2 * row + 1]             = p2 / dn;
                out[2 * NROWS + 2 * row]     = (float)e1;
                out[2 * NROWS + 2 * row + 1] = (float)e2;
            }
        }
        __syncthreads();
    }
}

extern "C" void kernel_launch(void* const* d_in, const int* in_sizes, int n_in,
                              void* d_out, int out_size, void* d_ws, size_t ws_size,
                              hipStream_t stream)
{
    const float* x  = (const float*)d_in[0];
    const float* gw = (const float*)d_in[1];
    float* out      = (float*)d_out;

    // d_ws layout: [wp 256KB][shard 2KB][cnt 4B pad->256B][list ...]
    unsigned short* wp = (unsigned short*)d_ws;
    float* shard   = (float*)((char*)d_ws + 262144);
    int*   cnt     = (int*)((char*)d_ws + 264192);
    int*   list    = (int*)((char*)d_ws + 264448);
    int cap = 0;
    if (ws_size >= 264448 + 4096) {
        size_t avail = (ws_size - 264448) / sizeof(int);
        cap = (avail > CAPMAX) ? CAPMAX : (int)avail;
    }

    const size_t lds_bytes = 16384;   // 2 x 8 KB x-tiles (reused for reduce)

    hipLaunchKernelGGL(wpack_kernel, dim3(64), dim3(256), 0, stream,
                       gw, wp, shard, cnt);
    hipLaunchKernelGGL(moe_main, dim3(NROWS / 32), dim3(256), lds_bytes, stream,
                       x, wp, out, shard, cnt, list, cap);
    hipLaunchKernelGGL(finalize_kernel, dim3(65), dim3(256), 0, stream,
                       x, gw, out, shard, cnt, list, cap);
}